// Round 4
// baseline (165.576 us; speedup 1.0000x reference)
//
#include <hip/hip_runtime.h>
#include <stdint.h>

#define NB_LAYERS 4
#define KSIZE 5
#define BSZ 8
#define LIN 2048
#define LSEQ 2049
#define CCH 32
#define HCH 16
#define MROWS (BSZ*LSEQ)          // 16392
#define NTILES ((MROWS+15)/16)    // 1025
#define NEG 0.1f
#define BNEPS 1e-5f
#define CONVGRID 205
#define CONVBLK 320               // 5 waves * 205 blocks = 1025 waves = NTILES
#define NFRAG 36                  // 32 K-frags + 2 k3b + 2 skip (x2 accumulators)
#define WT_HALVES (NFRAG*64*8)    // 18432 fp16 per layer

typedef _Float16 h2v __attribute__((ext_vector_type(2)));
typedef _Float16 h8v __attribute__((ext_vector_type(8)));
typedef float    f4v __attribute__((ext_vector_type(4)));

union H8 { h8v v; h2v h[4]; };

static __device__ __forceinline__ h2v mkh2(float a, float b) {
  h2v r; r[0] = (_Float16)a; r[1] = (_Float16)b; return r;
}

// decode one source element of a layer's weight table -> (dest half-index, value)
// source linear g: [0,16384) k3W slice, [16384,17408) k3b, [17408,18432) skipW
// dest layout: frag f (0..35) * 512 + lane(q<<4|m) * 8 + half(0..7); conflict-free b128 reads
static __device__ __forceinline__ void wt_decode(
    int g, const float* __restrict__ k3Wl, const float* __restrict__ k3bl,
    const float* __restrict__ skipWl, int& halfidx, float& val) {
  int n, k;
  if (g < 16384)      { n = g & 31; int c = (g >> 5) & 31; int h = g >> 10; k = h * 32 + c; val = k3Wl[g]; }
  else if (g < 17408) { int g2 = g - 16384; n = g2 & 31; int c = g2 >> 5; k = 512 + c; val = k3bl[g2]; }
  else                { int g2 = g - 17408; n = g2 & 31; int c = g2 >> 5; k = 544 + c; val = skipWl[g2]; }
  int m = n & 15, a = n >> 4, qq = (k >> 3) & 3, hh = k & 7;
  int f = (k < 512) ? ((k >> 5) * 2 + a) : ((k < 544) ? (32 + a) : (34 + a));
  halfidx = f * 512 + ((qq << 4) | m) * 8 + hh;
}

// ---------------- fused cont-conv layer ----------------
// MODE 0 (conv0): embedding fused, builds own LDS Wt from raw fp32, builds global Wt
//                 for layers 1-3, zeroes stats[1..3], inline BOS type-max, stats as
//                 per-block partial writes (no atomics, no pre-zero needed).
// MODE 1 (conv1-3): stages LDS Wt from global fp16 (linear copy), BN of previous layer
//                 fused into gathers (from partials reduce for conv1, from stats for
//                 conv2/3), stats via atomics into memory zeroed by conv0.
template<int MODE>
__global__ __launch_bounds__(CONVBLK) void conv_kernel(
    const float* __restrict__ enc_in,
    const int*   __restrict__ types,
    const float* __restrict__ emb,
    float* __restrict__ enc_out,
    const float* __restrict__ etimes,
    const float* __restrict__ k1Wp, const float* __restrict__ k1bp,
    const float* __restrict__ k2Wp, const float* __restrict__ k2bp,
    const float* __restrict__ k3W, const float* __restrict__ k3b,
    const float* __restrict__ skipW,
    _Float16* __restrict__ WtG,               // MODE0: base of 3-layer table (write); MODE1: this layer's slice (read)
    const float* __restrict__ stats_prev,     // conv2/3
    const float* __restrict__ partials_prev,  // conv1
    float* __restrict__ stats_out,            // conv1..3 atomic dest
    float* __restrict__ partials_out,         // conv0
    float* __restrict__ stats_zero,           // conv0: 192 floats (stats[1..3])
    const float* __restrict__ gamma_prev, const float* __restrict__ beta_prev,
    int dil)
{
  __shared__ h8v Wl[NFRAG * 64];                       // 36 KB weight table
  __shared__ h8v swh[(CONVBLK/64) * KSIZE * 16 * 2];   // MLP results
  __shared__ alignas(16) float sW[304];                // k1w|k1b|k2b|k2W
  __shared__ float sst[64];
  __shared__ float sbn[64];

  const int tid  = threadIdx.x;
  const int lane = tid & 63;
  const int wv   = tid >> 6;
  const int m    = lane & 15;     // A-frag row within tile / B-frag col n
  const int q    = lane >> 4;     // quad: k-subchunk + feat channels q*8..q*8+7

  // ---- staging phase ----
  if (tid < 64) sst[tid] = 0.f;
  if (tid < 16) { sW[tid] = k1Wp[tid]; sW[16 + tid] = k1bp[tid]; sW[32 + tid] = k2bp[tid]; }
  if (tid >= 64) sW[48 + tid - 64] = k2Wp[tid - 64];   // 256 entries, threads 64..319

  if (MODE == 0) {
    if (blockIdx.x == 0 && tid < 192) stats_zero[tid] = 0.f;
    // LDS Wt for layer 0 from raw fp32 (scattered ds_write_b16, one-time)
    for (int g = tid; g < WT_HALVES; g += CONVBLK) {
      int hi; float val;
      wt_decode(g, k3W, k3b, skipW, hi, val);
      ((_Float16*)Wl)[hi] = (_Float16)val;
    }
    // global fp16 Wt for layers 1..3: one element per thread grid-wide
    int id2 = blockIdx.x * CONVBLK + tid;
    if (id2 < 3 * WT_HALVES) {
      int layer = 1 + id2 / WT_HALVES;
      int g = id2 - (layer - 1) * WT_HALVES;
      int hi; float val;
      wt_decode(g, k3W + layer * 16384, k3b + layer * 1024, skipW + layer * 1024, hi, val);
      WtG[(layer - 1) * WT_HALVES + hi] = (_Float16)val;
    }
  } else {
    // linear 36KB copy: global fp16 -> LDS (coalesced, conflict-free)
    const float4* src = (const float4*)WtG;
    float4* dst = (float4*)Wl;
    for (int i = tid; i < WT_HALVES / 8; i += CONVBLK) dst[i] = src[i];
    if (partials_prev && tid < 64) sbn[tid] = 0.f;
  }
  __syncthreads();

  // conv1 only: reduce layer-0 per-block stat partials (320 % 64 == 0 -> each thread
  // sums a single channel-column; coalesced loads, one LDS atomic per thread)
  if (MODE == 1 && partials_prev) {
    float v = 0.f;
    for (int i = tid; i < CONVGRID * 64; i += CONVBLK) v += partials_prev[i];
    atomicAdd(&sbn[tid & 63], v);
    __syncthreads();
  }

  // BN of previous layer, fused into loads: x -> leaky(x*sc + ob)
  float sc8[8], ob8[8];
  if (MODE == 1) {
    const float inv = 1.f / (float)MROWS;
#pragma unroll
    for (int j = 0; j < 8; j++) {
      int c = q * 8 + j;
      float s1 = partials_prev ? sbn[c]      : stats_prev[c];
      float s2 = partials_prev ? sbn[32 + c] : stats_prev[32 + c];
      float mu = s1 * inv;
      float var = s2 * inv - mu * mu;
      float sc = gamma_prev[c] * rsqrtf(var + BNEPS);
      sc8[j] = sc; ob8[j] = beta_prev[c] - mu * sc;
    }
  }

  const int tile = blockIdx.x * (CONVBLK / 64) + wv;   // exactly one tile per wave
  int row = tile * 16 + m;
  bool rvalid = row < MROWS;
  int rowc = min(row, MROWS - 1);
  int b = rowc / LSEQ, pos = rowc % LSEQ;
  float t_l = (pos == 0) ? 0.f : etimes[b * LIN + pos - 1];
  bool mask_l = rvalid && (t_l != 0.f);

  // BOS embedding index: inline scan of types (only waves containing a pos==0 row; 8 of 1025)
  int bosv = 0;
  if (MODE == 0) {
    if (__ballot(pos == 0)) {
      int mx = 0;
#pragma unroll 8
      for (int i = lane; i < BSZ * LIN; i += 64) mx = max(mx, types[i]);
#pragma unroll
      for (int off = 32; off; off >>= 1) mx = max(mx, __shfl_xor(mx, off, 64));
      bosv = mx + 1;
    }
  }

  // ---- phase G: prefetch all gather data, then transform ----
  int jcs[KSIZE]; float tjv[KSIZE];
#pragma unroll
  for (int tap = 0; tap < KSIZE; tap++) {
    int j = pos - tap * dil;
    int jc = max(j, 0); jcs[tap] = jc;
    tjv[tap] = (jc == 0) ? 0.f : etimes[b * LIN + jc - 1];
  }
  float4 fa[KSIZE], fbv[KSIZE];
  int tts[KSIZE];
  if (MODE == 0) {
#pragma unroll
    for (int tap = 0; tap < KSIZE; tap++) {
      int jc = jcs[tap];
      tts[tap] = (jc > 0) ? types[b * LIN + jc - 1] : ((tap == 0) ? bosv : 0);
    }
#pragma unroll
    for (int tap = 0; tap < KSIZE; tap++) {
      const float* ep = emb + tts[tap] * CCH + q * 8;
      fa[tap] = *(const float4*)ep; fbv[tap] = *(const float4*)(ep + 4);
    }
  } else {
#pragma unroll
    for (int tap = 0; tap < KSIZE; tap++) {
      const float* fp = enc_in + (b * LSEQ + jcs[tap]) * CCH + q * 8;
      fa[tap] = *(const float4*)fp; fbv[tap] = *(const float4*)(fp + 4);
    }
  }

  h2v fh[KSIZE][4];     // gathered feats (fp16 pairs)
  h2v fself[4];
  float Fb[8];
#pragma unroll
  for (int jj = 0; jj < 8; jj++) Fb[jj] = 0.f;

#pragma unroll
  for (int tap = 0; tap < KSIZE; tap++) {
    bool gm = mask_l && (pos - tap * dil >= 0) && (tjv[tap] != 0.f);
    float fv[8] = {fa[tap].x, fa[tap].y, fa[tap].z, fa[tap].w,
                   fbv[tap].x, fbv[tap].y, fbv[tap].z, fbv[tap].w};
    if (MODE == 0) {
      float zf = (tts[tap] != 0) ? 1.f : 0.f;
#pragma unroll
      for (int jj = 0; jj < 8; jj++) fv[jj] *= zf;
    } else {
#pragma unroll
      for (int jj = 0; jj < 8; jj++) {
        float x = fmaf(fv[jj], sc8[jj], ob8[jj]);
        fv[jj] = fmaxf(x, NEG * x);
      }
    }
    if (tap == 0) {
      float rv = rvalid ? 1.f : 0.f;
#pragma unroll
      for (int p2 = 0; p2 < 4; p2++) fself[p2] = mkh2(fv[2*p2] * rv, fv[2*p2+1] * rv);
    }
    float g = gm ? 1.f : 0.f;
#pragma unroll
    for (int jj = 0; jj < 8; jj++) Fb[jj] += g * fv[jj];
#pragma unroll
    for (int p2 = 0; p2 < 4; p2++) fh[tap][p2] = mkh2(fv[2*p2], fv[2*p2+1]);
  }

  // ---- phase M: 80 (row,tap) MLP jobs distributed over lanes ----
#pragma unroll
  for (int rep = 0; rep < 2; rep++) {
    const int jt = rep ? (KSIZE - 1) : (lane >> 4);
    const bool act = rep ? (lane < 16) : true;
    int j2 = pos - jt * dil;
    int jc2 = max(j2, 0);
    float tj2 = (jc2 == 0) ? 0.f : etimes[b * LIN + jc2 - 1];
    bool g2 = act && mask_l && (j2 >= 0) && (tj2 != 0.f);
    float dt = g2 ? (t_l - tj2) : 0.f;

    H8 w0, w1;
    if (__ballot(g2)) {
      const f4v* k1wv = (const f4v*)&sW[0];
      const f4v* k1bv = (const f4v*)&sW[16];
      const f4v* k2bv = (const f4v*)&sW[32];
      float h1[HCH], h2[HCH];
#pragma unroll
      for (int h4 = 0; h4 < 4; h4++) {
        f4v cw = k1wv[h4], cb = k1bv[h4], c2 = k2bv[h4];
#pragma unroll
        for (int r = 0; r < 4; r++) {
          float x = fmaf(dt, cw[r], cb[r]);
          h1[h4*4+r] = fmaxf(x, NEG * x);
          h2[h4*4+r] = c2[r];
        }
      }
#pragma unroll
      for (int hp = 0; hp < HCH; hp++) {
        float hv = h1[hp];
        const f4v* kk = (const f4v*)&sW[48 + hp * 16];
#pragma unroll
        for (int h4 = 0; h4 < 4; h4++) {
          f4v c = kk[h4];
#pragma unroll
          for (int r = 0; r < 4; r++) h2[h4*4+r] = fmaf(hv, c[r], h2[h4*4+r]);
        }
      }
      float g = g2 ? 1.f : 0.f;
#pragma unroll
      for (int p2 = 0; p2 < 4; p2++) {
        float a0 = h2[2*p2];     a0 = fmaxf(a0, NEG * a0) * g;
        float a1 = h2[2*p2+1];   a1 = fmaxf(a1, NEG * a1) * g;
        w0.h[p2] = mkh2(a0, a1);
        float b0 = h2[8+2*p2];   b0 = fmaxf(b0, NEG * b0) * g;
        float b1 = h2[8+2*p2+1]; b1 = fmaxf(b1, NEG * b1) * g;
        w1.h[p2] = mkh2(b0, b1);
      }
    } else {
#pragma unroll
      for (int p2 = 0; p2 < 4; p2++) { w0.h[p2] = mkh2(0.f, 0.f); w1.h[p2] = mkh2(0.f, 0.f); }
    }
    if (act) {
      int base = ((wv * KSIZE + jt) * 16 + m) * 2;
      swh[base] = w0.v; swh[base + 1] = w1.v;
    }
  }
  __syncthreads();

  // ---- phase U: read wh, pack A-frags, MFMA against LDS B-frags ----
  h2v wh[KSIZE][8];
#pragma unroll
  for (int tap = 0; tap < KSIZE; tap++) {
    int base = ((wv * KSIZE + tap) * 16 + m) * 2;
    H8 a0, a1; a0.v = swh[base]; a1.v = swh[base + 1];
#pragma unroll
    for (int p2 = 0; p2 < 4; p2++) { wh[tap][p2] = a0.h[p2]; wh[tap][4+p2] = a1.h[p2]; }
  }

  f4v aP = {0,0,0,0}, aQ = {0,0,0,0}, bP = {0,0,0,0}, bQ = {0,0,0,0};

#pragma unroll
  for (int ks = 0; ks < 16; ks++) {
    H8 bf0, bf1, af;
    bf0.v = Wl[(2*ks + 0) * 64 + lane];
    bf1.v = Wl[(2*ks + 1) * 64 + lane];
    h2v u0 = mkh2(0.f,0.f), u1 = mkh2(0.f,0.f), u2 = mkh2(0.f,0.f), u3 = mkh2(0.f,0.f);
#pragma unroll
    for (int tap = 0; tap < KSIZE; tap++) {
      _Float16 w = wh[tap][ks >> 1][ks & 1];
      h2v wd; wd[0] = w; wd[1] = w;
      u0 += wd * fh[tap][0];
      u1 += wd * fh[tap][1];
      u2 += wd * fh[tap][2];
      u3 += wd * fh[tap][3];
    }
    af.h[0] = u0; af.h[1] = u1; af.h[2] = u2; af.h[3] = u3;
    if (ks & 1) {
      aQ = __builtin_amdgcn_mfma_f32_16x16x32_f16(af.v, bf0.v, aQ, 0, 0, 0);
      bQ = __builtin_amdgcn_mfma_f32_16x16x32_f16(af.v, bf1.v, bQ, 0, 0, 0);
    } else {
      aP = __builtin_amdgcn_mfma_f32_16x16x32_f16(af.v, bf0.v, aP, 0, 0, 0);
      bP = __builtin_amdgcn_mfma_f32_16x16x32_f16(af.v, bf1.v, bP, 0, 0, 0);
    }
  }
  { // k3b block
    H8 bf0, bf1, af;
    bf0.v = Wl[32 * 64 + lane];
    bf1.v = Wl[33 * 64 + lane];
#pragma unroll
    for (int p2 = 0; p2 < 4; p2++) af.h[p2] = mkh2(Fb[2*p2], Fb[2*p2+1]);
    aP = __builtin_amdgcn_mfma_f32_16x16x32_f16(af.v, bf0.v, aP, 0, 0, 0);
    bP = __builtin_amdgcn_mfma_f32_16x16x32_f16(af.v, bf1.v, bP, 0, 0, 0);
  }
  { // skip block
    H8 bf0, bf1, af;
    bf0.v = Wl[34 * 64 + lane];
    bf1.v = Wl[35 * 64 + lane];
    af.h[0] = fself[0]; af.h[1] = fself[1]; af.h[2] = fself[2]; af.h[3] = fself[3];
    aQ = __builtin_amdgcn_mfma_f32_16x16x32_f16(af.v, bf0.v, aQ, 0, 0, 0);
    bQ = __builtin_amdgcn_mfma_f32_16x16x32_f16(af.v, bf1.v, bQ, 0, 0, 0);
  }
  f4v acc0 = aP + aQ;
  f4v acc1 = bP + bQ;

  // epilogue: store + BN stats.  D layout: col = lane&15, row = (lane>>4)*4 + r
  float s0 = 0.f, s1 = 0.f, s2 = 0.f, s3 = 0.f;
#pragma unroll
  for (int r = 0; r < 4; r++) {
    float v0 = acc0[r], v1 = acc1[r];
    s0 += v0; s1 += v0 * v0; s2 += v1; s3 += v1 * v1;
    int rd = tile * 16 + q * 4 + r;
    if (rd < MROWS) {
      enc_out[rd * CCH + m] = v0;
      enc_out[rd * CCH + 16 + m] = v1;
    }
  }
  s0 += __shfl_xor(s0, 16, 64); s0 += __shfl_xor(s0, 32, 64);
  s1 += __shfl_xor(s1, 16, 64); s1 += __shfl_xor(s1, 32, 64);
  s2 += __shfl_xor(s2, 16, 64); s2 += __shfl_xor(s2, 32, 64);
  s3 += __shfl_xor(s3, 16, 64); s3 += __shfl_xor(s3, 32, 64);
  if (q == 0) {
    atomicAdd(&sst[m], s0);
    atomicAdd(&sst[32 + m], s1);
    atomicAdd(&sst[16 + m], s2);
    atomicAdd(&sst[48 + m], s3);
  }
  __syncthreads();
  if (tid < 64) {
    if (MODE == 0) partials_out[blockIdx.x * 64 + tid] = sst[tid];
    else           atomicAdd(&stats_out[tid], sst[tid]);
  }
}

// ---------------- final BN + leaky-relu ----------------
// grid: 2049 x 256 (MROWS*CCH exactly)
__global__ __launch_bounds__(256) void bn_kernel(
    const float* __restrict__ x, float* __restrict__ out,
    const float* __restrict__ stats,
    const float* __restrict__ gamma, const float* __restrict__ beta) {
  int id = blockIdx.x * blockDim.x + threadIdx.x;
  int c = id & 31;
  const float inv = 1.f / (float)MROWS;
  float mu = stats[c] * inv;
  float var = stats[32 + c] * inv - mu * mu;
  float sc = gamma[c] * rsqrtf(var + BNEPS);
  float v = fmaf(x[id], sc, beta[c] - mu * sc);
  out[id] = fmaxf(v, NEG * v);
}

extern "C" void kernel_launch(void* const* d_in, const int* in_sizes, int n_in,
                              void* d_out, int out_size, void* d_ws, size_t ws_size,
                              hipStream_t stream) {
  (void)in_sizes; (void)n_in; (void)out_size; (void)ws_size;
  const float* event_times = (const float*)d_in[0];
  const int*   event_types = (const int*)d_in[1];
  const float* emb   = (const float*)d_in[2];
  const float* k1W   = (const float*)d_in[3];
  const float* k1b   = (const float*)d_in[4];
  const float* k2W   = (const float*)d_in[5];
  const float* k2b   = (const float*)d_in[6];
  const float* k3W   = (const float*)d_in[7];
  const float* k3b   = (const float*)d_in[8];
  const float* skipW = (const float*)d_in[9];
  // d_in[10] = skipb: BN-invariant, dropped
  const float* gamma = (const float*)d_in[11];
  const float* beta  = (const float*)d_in[12];

  float* enc_a = (float*)d_ws;
  float* enc_b = enc_a + (size_t)MROWS * CCH;
  float* stats = enc_b + (size_t)MROWS * CCH;          // 4*64 floats; [0] unused, [1..3] atomic dests
  float* partials0 = stats + NB_LAYERS * 64;           // 205*64 floats
  _Float16* WtG = (_Float16*)(((uintptr_t)(partials0 + CONVGRID * 64) + 255) & ~(uintptr_t)255);

  // layer 0: embedding fused, builds Wt tables, zeroes stats[1..3], partial stats out
  conv_kernel<0><<<CONVGRID, CONVBLK, 0, stream>>>(
      nullptr, event_types, emb, enc_b, event_times,
      k1W, k1b, k2W, k2b, k3W, k3b, skipW, WtG,
      nullptr, nullptr, nullptr, partials0, stats + 64,
      nullptr, nullptr, 1);

  // layer 1: reduce layer-0 partials for BN; atomic stats into stats[1]
  conv_kernel<1><<<CONVGRID, CONVBLK, 0, stream>>>(
      enc_b, nullptr, nullptr, enc_a, event_times,
      k1W + HCH, k1b + HCH, k2W + HCH*HCH, k2b + HCH,
      nullptr, nullptr, nullptr, WtG + 0 * WT_HALVES,
      nullptr, partials0, stats + 64, nullptr, nullptr,
      gamma + 0 * CCH, beta + 0 * CCH, 2);

  // layer 2
  conv_kernel<1><<<CONVGRID, CONVBLK, 0, stream>>>(
      enc_a, nullptr, nullptr, enc_b, event_times,
      k1W + 2*HCH, k1b + 2*HCH, k2W + 2*HCH*HCH, k2b + 2*HCH,
      nullptr, nullptr, nullptr, WtG + 1 * WT_HALVES,
      stats + 64, nullptr, stats + 128, nullptr, nullptr,
      gamma + 1 * CCH, beta + 1 * CCH, 4);

  // layer 3
  conv_kernel<1><<<CONVGRID, CONVBLK, 0, stream>>>(
      enc_b, nullptr, nullptr, enc_a, event_times,
      k1W + 3*HCH, k1b + 3*HCH, k2W + 3*HCH*HCH, k2b + 3*HCH,
      nullptr, nullptr, nullptr, WtG + 2 * WT_HALVES,
      stats + 128, nullptr, stats + 192, nullptr, nullptr,
      gamma + 2 * CCH, beta + 2 * CCH, 8);

  // final BN+leaky of layer 3
  bn_kernel<<<2049, 256, 0, stream>>>(enc_a, (float*)d_out,
      stats + 192, gamma + 3 * CCH, beta + 3 * CCH);
}